// Round 5
// baseline (722.720 us; speedup 1.0000x reference)
//
#include <hip/hip_runtime.h>
#include <cstdint>

#define N_NODES 100000
#define N_EDGES 1600000
#define ETOT    1700000   // edges + self loops
#define FIN     512
#define HD1     64        // 8 heads * 8 dims
#define C2      40
#define NEG_SLOPE 0.2f
#define DEG_NB   480      // degord blocks (dispatched FIRST)
#define GEMM1_NB 782      // ceil(N_NODES/128)
#define SCAN_NB2 98       // ceil(N_NODES/1024), all-resident lookback scan

typedef __attribute__((ext_vector_type(8))) short bf16x8;
typedef __attribute__((ext_vector_type(4))) float f32x4;

__device__ __forceinline__ float lrelu(float v) { return v > 0.f ? v : NEG_SLOPE * v; }

__device__ __forceinline__ unsigned short f2bf(float f) {
    uint32_t u = __float_as_uint(f);
    u += 0x7FFF + ((u >> 16) & 1);   // round-to-nearest-even
    return (unsigned short)(u >> 16);
}
__device__ __forceinline__ float bf2f(unsigned short u) {
    return __uint_as_float(((uint32_t)u) << 16);
}

// ---------------- prep (merged) + zero deg + zero scan flags ----------------
__global__ void k_prep(const float* __restrict__ W1, const float* __restrict__ a_s,
                       const float* __restrict__ a_d,
                       const float* __restrict__ W2, const float* __restrict__ att_s2,
                       const float* __restrict__ att_d2,
                       unsigned short* __restrict__ W1t, unsigned short* __restrict__ W2t,
                       int* __restrict__ deg, unsigned int* __restrict__ flags) {
    int i = blockIdx.x * 256 + threadIdx.x;
    if (i < N_NODES) deg[i] = 0;
    if (i < 128) flags[i] = 0u;
    if (i < 80 * 512) {
        int n = i >> 9, k = i & 511;
        float v;
        if (n < 64) {
            v = W1[k * HD1 + n];
        } else if (n < 72) {
            int h = n - 64; v = 0.f;
#pragma unroll
            for (int d = 0; d < 8; d++) v += W1[k * HD1 + h * 8 + d] * a_s[h * 8 + d];
        } else {
            int h = n - 72; v = 0.f;
#pragma unroll
            for (int d = 0; d < 8; d++) v += W1[k * HD1 + h * 8 + d] * a_d[h * 8 + d];
        }
        W1t[n * FIN + k] = f2bf(v);
    } else if (i < 80 * 512 + 48 * 64) {
        int j = i - 80 * 512;
        int n = j >> 6, k = j & 63;
        float v = 0.f;
        if (n < C2) {
            v = W2[k * C2 + n];
        } else if (n == C2) {
            for (int c = 0; c < C2; c++) v += W2[k * C2 + c] * att_s2[c];
        } else if (n == C2 + 1) {
            for (int c = 0; c < C2; c++) v += W2[k * C2 + c] * att_d2[c];
        }
        W2t[n * 64 + k] = f2bf(v);
    }
}

// ---------------- merged: degord (blocks 0..DEG_NB-1, dispatched FIRST) || GEMM1 ------
// Atomic pass starts at t=0; gemm1 streams underneath it on the data path.
__global__ __launch_bounds__(256) void k_g1deg(const float* __restrict__ x,
                                               const unsigned short* __restrict__ W1t,
                                               unsigned short* __restrict__ h1b,
                                               float* __restrict__ as1,
                                               float* __restrict__ ad1,
                                               const int* __restrict__ ei,
                                               int* __restrict__ deg,
                                               int* __restrict__ ord) {
    __shared__ unsigned short As[128 * 72];   // chunk of x in bf16, row stride 72 (pad 8)
    const int t = threadIdx.x;
    if (blockIdx.x < DEG_NB) {
        // ---- degord: degree + per-edge rank in one atomic pass ----
        for (int e = (int)blockIdx.x * 256 + t; e < ETOT; e += DEG_NB * 256) {
            int dst = (e < N_EDGES) ? ei[N_EDGES + e] : e - N_EDGES;
            ord[e] = atomicAdd(&deg[dst], 1);
        }
        return;
    }
    const int lane = t & 63, wv = t >> 6;
    const int quad = lane >> 4, l16 = lane & 15;
    const int row0 = ((int)blockIdx.x - DEG_NB) * 128;

    f32x4 acc[2][5];
#pragma unroll
    for (int mi = 0; mi < 2; mi++)
#pragma unroll
        for (int ni = 0; ni < 5; ni++) acc[mi][ni] = (f32x4){0.f, 0.f, 0.f, 0.f};

    float4 rx[8];
#pragma unroll
    for (int i = 0; i < 8; i++) {
        int ff = t + i * 256;
        int r = ff >> 4, c4 = ff & 15;
        int row = row0 + r;
        rx[i] = (row < N_NODES) ? *(const float4*)&x[(size_t)row * FIN + c4 * 4]
                                : make_float4(0.f, 0.f, 0.f, 0.f);
    }

    for (int c = 0; c < 8; c++) {
#pragma unroll
        for (int i = 0; i < 8; i++) {
            int ff = t + i * 256;
            int r = ff >> 4, c4 = ff & 15;
            ushort4 s4;
            s4.x = f2bf(rx[i].x); s4.y = f2bf(rx[i].y);
            s4.z = f2bf(rx[i].z); s4.w = f2bf(rx[i].w);
            *(ushort4*)&As[r * 72 + c4 * 4] = s4;
        }
        __syncthreads();
        if (c < 7) {
            int kb = (c + 1) * 64;
#pragma unroll
            for (int i = 0; i < 8; i++) {
                int ff = t + i * 256;
                int r = ff >> 4, c4 = ff & 15;
                int row = row0 + r;
                rx[i] = (row < N_NODES) ? *(const float4*)&x[(size_t)row * FIN + kb + c4 * 4]
                                        : make_float4(0.f, 0.f, 0.f, 0.f);
            }
        }
        int kb = c * 64;
#pragma unroll
        for (int ks = 0; ks < 2; ks++) {
            bf16x8 af[2], bfv[5];
#pragma unroll
            for (int mi = 0; mi < 2; mi++) {
                int lr = wv * 32 + mi * 16 + l16;
                af[mi] = *(const bf16x8*)&As[lr * 72 + ks * 32 + quad * 8];
            }
#pragma unroll
            for (int ni = 0; ni < 5; ni++) {
                int n = ni * 16 + l16;
                bfv[ni] = *(const bf16x8*)&W1t[n * FIN + kb + ks * 32 + quad * 8];
            }
#pragma unroll
            for (int mi = 0; mi < 2; mi++)
#pragma unroll
                for (int ni = 0; ni < 5; ni++)
                    acc[mi][ni] = __builtin_amdgcn_mfma_f32_16x16x32_bf16(
                        af[mi], bfv[ni], acc[mi][ni], 0, 0, 0);
        }
        __syncthreads();
    }
#pragma unroll
    for (int mi = 0; mi < 2; mi++)
#pragma unroll
        for (int ni = 0; ni < 5; ni++)
#pragma unroll
            for (int r = 0; r < 4; r++) {
                int row = row0 + wv * 32 + mi * 16 + quad * 4 + r;
                if (row >= N_NODES) continue;
                int col = ni * 16 + l16;
                float v = acc[mi][ni][r];
                if (col < 64)       h1b[(size_t)row * 64 + col] = f2bf(v);
                else if (col < 72)  as1[row * 8 + (col - 64)] = v;
                else                ad1[row * 8 + (col - 72)] = v;
            }
}

// ---------------- single-kernel decoupled-lookback scan: deg -> row_ptr (exclusive) ------
// 98 blocks <= 256 CUs -> all blocks co-resident -> predecessor spin always terminates.
__global__ __launch_bounds__(1024) void k_scan_lb(const int* __restrict__ deg,
                                                  int* __restrict__ row_ptr,
                                                  int* __restrict__ aggr,
                                                  int* __restrict__ incl,
                                                  unsigned int* __restrict__ flags) {
    __shared__ int sh[1024];
    __shared__ int shbase;
    const int t = threadIdx.x, b = blockIdx.x;
    const int i = b * 1024 + t;
    int v = (i < N_NODES) ? deg[i] : 0;
    sh[t] = v;
    __syncthreads();
    for (int off = 1; off < 1024; off <<= 1) {
        int u = (t >= off) ? sh[t - off] : 0;
        __syncthreads();
        sh[t] += u;
        __syncthreads();
    }
    if (t == 0) {
        int total = sh[1023];
        int run = 0;
        if (b == 0) {
            __hip_atomic_store(&incl[0], total, __ATOMIC_RELEASE, __HIP_MEMORY_SCOPE_AGENT);
            __hip_atomic_store(&flags[0], 2u, __ATOMIC_RELEASE, __HIP_MEMORY_SCOPE_AGENT);
        } else {
            __hip_atomic_store(&aggr[b], total, __ATOMIC_RELEASE, __HIP_MEMORY_SCOPE_AGENT);
            __hip_atomic_store(&flags[b], 1u, __ATOMIC_RELEASE, __HIP_MEMORY_SCOPE_AGENT);
            int p = b - 1;
            while (true) {
                unsigned int f = __hip_atomic_load(&flags[p], __ATOMIC_ACQUIRE,
                                                   __HIP_MEMORY_SCOPE_AGENT);
                if (f == 2u) {
                    run += __hip_atomic_load(&incl[p], __ATOMIC_ACQUIRE,
                                             __HIP_MEMORY_SCOPE_AGENT);
                    break;
                } else if (f == 1u) {
                    run += __hip_atomic_load(&aggr[p], __ATOMIC_ACQUIRE,
                                             __HIP_MEMORY_SCOPE_AGENT);
                    --p;
                }
            }
            __hip_atomic_store(&incl[b], run + total, __ATOMIC_RELEASE,
                               __HIP_MEMORY_SCOPE_AGENT);
            __hip_atomic_store(&flags[b], 2u, __ATOMIC_RELEASE, __HIP_MEMORY_SCOPE_AGENT);
        }
        shbase = run;
        if (b == 0) row_ptr[N_NODES] = ETOT;   // scan total is a compile-time constant
    }
    __syncthreads();
    int base = shbase;
    if (i < N_NODES) row_ptr[i] = base + sh[t] - v;
}

// scatter with precomputed rank — no atomics
__global__ void k_scatter(const int* __restrict__ ei, const int* __restrict__ row_ptr,
                          const int* __restrict__ ord, int* __restrict__ csr_src) {
    int e = blockIdx.x * 256 + threadIdx.x;
    if (e >= ETOT) return;
    int src, dst;
    if (e < N_EDGES) { src = ei[e]; dst = ei[N_EDGES + e]; }
    else             { src = dst = e - N_EDGES; }
    csr_src[row_ptr[dst] + ord[e]] = src;
}

// ---------------- layer 1 FUSED with gemm2:
// gather-aggregate + bias + ELU -> h (in regs) -> matvec with W2t -> [h2b | as2 | ad2]
// one wave per dst; lane = (edge-slot g = lane>>3, head i8 = lane&7)
// 16 edges in flight per step (two independent 8-edge groups).
__global__ __launch_bounds__(256) void k_agg1f(
    const unsigned short* __restrict__ h1b,
    const float* __restrict__ as1, const float* __restrict__ ad1,
    const int* __restrict__ row_ptr, const int* __restrict__ csr_src,
    const float* __restrict__ b1, const unsigned short* __restrict__ W2t,
    unsigned short* __restrict__ h2b, float* __restrict__ as2,
    float* __restrict__ ad2) {
    __shared__ float w2l[64][48];   // W2t transposed to f32: w2l[k][c] = W2[k][c]-ish
    int t = threadIdx.x, wv = t >> 6, lane = t & 63;
    for (int i = t; i < 64 * 48; i += 256) {
        int k = i / 48, c = i - k * 48;
        w2l[k][c] = bf2f(W2t[c * 64 + k]);
    }
    __syncthreads();

    int dst = blockIdx.x * 4 + wv;             // grid exact: dst < N_NODES always
    int g = lane >> 3, i8 = lane & 7;
    int s0 = row_ptr[dst], s1e = row_ptr[dst + 1];
    float adh = ad1[dst * 8 + i8];
    float den = 0.f;
    float facc[8];
#pragma unroll
    for (int d = 0; d < 8; d++) facc[d] = 0.f;

    for (int base = s0; base < s1e; base += 64) {
        int idx = base + lane;
        int sl = (idx < s1e) ? csr_src[idx] : 0;
        int cnt = min(64, s1e - base);
        for (int j = 0; j < cnt; j += 16) {
            int sA = __shfl(sl, j + g);
            int sB = __shfl(sl, j + 8 + g);
            bool vA = (j + g) < cnt, vB = (j + 8 + g) < cnt;
            bf16x8 rA = *(const bf16x8*)&h1b[(size_t)sA * 64 + i8 * 8];
            bf16x8 rB = *(const bf16x8*)&h1b[(size_t)sB * 64 + i8 * 8];
            float aA = as1[sA * 8 + i8];
            float aB = as1[sB * 8 + i8];
            float wA = vA ? __expf(lrelu(aA + adh)) : 0.f;
            float wB = vB ? __expf(lrelu(aB + adh)) : 0.f;
            den += wA + wB;
#pragma unroll
            for (int d = 0; d < 8; d++)
                facc[d] += wA * bf2f((unsigned short)rA[d]) +
                           wB * bf2f((unsigned short)rB[d]);
        }
    }
    // reduce across edge-slots g (lane bits 3..5) — afterwards all lanes hold totals
#pragma unroll
    for (int o = 8; o <= 32; o <<= 1) {
        den += __shfl_xor(den, o, 64);
#pragma unroll
        for (int d = 0; d < 8; d++) facc[d] += __shfl_xor(facc[d], o, 64);
    }
    float rden = 1.f / (den + 1e-16f);
    float4 b1lo = *(const float4*)&b1[i8 * 8];
    float4 b1hi = *(const float4*)&b1[i8 * 8 + 4];
    float bb[8] = {b1lo.x, b1lo.y, b1lo.z, b1lo.w, b1hi.x, b1hi.y, b1hi.z, b1hi.w};
    float hv[8];
#pragma unroll
    for (int d = 0; d < 8; d++) {
        float v = facc[d] * rden + bb[d];
        hv[d] = v > 0.f ? v : expm1f(v);
    }
    // ---- in-wave matvec: out[c] = sum_k h[k] * W2t[c][k]; lane c computes out[c] ----
    // h[k] for k = ks*8+d lives in lane (g=0,i8=ks) reg hv[d] -> broadcast via shfl.
    int cidx = lane < 48 ? lane : 0;
    float out = 0.f;
#pragma unroll
    for (int ks = 0; ks < 8; ks++) {
#pragma unroll
        for (int d = 0; d < 8; d++) {
            float hk = __shfl(hv[d], ks);
            out += hk * w2l[ks * 8 + d][cidx];
        }
    }
    if (lane < C2)            h2b[(size_t)dst * C2 + lane] = f2bf(out);
    else if (lane == C2)      as2[dst] = out;
    else if (lane == C2 + 1)  ad2[dst] = out;
}

// ---------------- layer 2: gather-aggregate + bias + log_softmax ----------------
// one wave per dst; lane = (edge-slot g = lane>>3, chunk i8 = lane&7); chunks 0..4 active
// 16 edges per step (two independent 8-edge groups).
__global__ __launch_bounds__(256) void k_agg2(
    const unsigned short* __restrict__ h2b,
    const float* __restrict__ as2, const float* __restrict__ ad2,
    const int* __restrict__ row_ptr, const int* __restrict__ csr_src,
    const float* __restrict__ b2, float* __restrict__ out) {
    int t = threadIdx.x, wv = t >> 6, lane = t & 63;
    int dst = blockIdx.x * 4 + wv;
    if (dst >= N_NODES) return;
    int g = lane >> 3, i8 = lane & 7;
    bool act = i8 < 5;
    int off = act ? i8 * 8 : 0;
    int s0 = row_ptr[dst], s1e = row_ptr[dst + 1];
    float ad = ad2[dst];
    float denp = 0.f;
    float facc[8];
#pragma unroll
    for (int d = 0; d < 8; d++) facc[d] = 0.f;

    for (int base = s0; base < s1e; base += 64) {
        int idx = base + lane;
        int sl = (idx < s1e) ? csr_src[idx] : 0;
        int cnt = min(64, s1e - base);
        for (int j = 0; j < cnt; j += 16) {
            int sA = __shfl(sl, j + g);
            int sB = __shfl(sl, j + 8 + g);
            bool vA = (j + g) < cnt, vB = (j + 8 + g) < cnt;
            bf16x8 rA = *(const bf16x8*)&h2b[(size_t)sA * C2 + off];
            bf16x8 rB = *(const bf16x8*)&h2b[(size_t)sB * C2 + off];
            float aA = as2[sA];
            float aB = as2[sB];
            float wfA = vA ? __expf(lrelu(aA + ad)) : 0.f;
            float wfB = vB ? __expf(lrelu(aB + ad)) : 0.f;
            if (i8 == 0) denp += wfA + wfB;                // each edge counted once
            float wA = act ? wfA : 0.f;
            float wB = act ? wfB : 0.f;
#pragma unroll
            for (int d = 0; d < 8; d++)
                facc[d] += wA * bf2f((unsigned short)rA[d]) +
                           wB * bf2f((unsigned short)rB[d]);
        }
    }
    // facc: reduce across edge-slots g (bits 3..5)
#pragma unroll
    for (int o = 8; o <= 32; o <<= 1)
#pragma unroll
        for (int d = 0; d < 8; d++) facc[d] += __shfl_xor(facc[d], o, 64);
    // den: full 64-lane butterfly of the i8==0 partials
    float den = denp;
#pragma unroll
    for (int o = 32; o >= 1; o >>= 1) den += __shfl_xor(den, o, 64);
    float rden = 1.f / (den + 1e-16f);

    float vch[8];
    float mx = -1e30f;
#pragma unroll
    for (int d = 0; d < 8; d++) {
        vch[d] = act ? facc[d] * rden + b2[off + d] : -1e30f;
        mx = fmaxf(mx, vch[d]);
    }
#pragma unroll
    for (int o = 1; o <= 4; o <<= 1) mx = fmaxf(mx, __shfl_xor(mx, o, 64));
    float es = 0.f;
#pragma unroll
    for (int d = 0; d < 8; d++) es += act ? __expf(vch[d] - mx) : 0.f;
#pragma unroll
    for (int o = 1; o <= 4; o <<= 1) es += __shfl_xor(es, o, 64);
    float lg = logf(es);
    if (g == 0 && act) {
        float4 o0 = {vch[0] - mx - lg, vch[1] - mx - lg, vch[2] - mx - lg, vch[3] - mx - lg};
        float4 o1 = {vch[4] - mx - lg, vch[5] - mx - lg, vch[6] - mx - lg, vch[7] - mx - lg};
        *(float4*)&out[(size_t)dst * C2 + i8 * 8]     = o0;
        *(float4*)&out[(size_t)dst * C2 + i8 * 8 + 4] = o1;
    }
}

extern "C" void kernel_launch(void* const* d_in, const int* in_sizes, int n_in,
                              void* d_out, int out_size, void* d_ws, size_t ws_size,
                              hipStream_t stream) {
    const float* x     = (const float*)d_in[0];
    const int*   ei    = (const int*)d_in[1];
    const float* W1    = (const float*)d_in[2];
    const float* at_s1 = (const float*)d_in[3];
    const float* at_d1 = (const float*)d_in[4];
    const float* b1    = (const float*)d_in[5];
    const float* W2    = (const float*)d_in[6];
    const float* at_s2 = (const float*)d_in[7];
    const float* at_d2 = (const float*)d_in[8];
    const float* b2    = (const float*)d_in[9];
    float* out = (float*)d_out;
    float* ws  = (float*)d_ws;

    // workspace layout (float-element offsets) — NON-OVERLAPPING:
    unsigned short* h1b = (unsigned short*)ws;                 // [0, 3.2M)  N*64 bf16
    float* as1 = ws + 3200000;                                 // [3.2M,4.0M)
    float* ad1 = ws + 4000000;                                 // [4.0M,4.8M)
    unsigned short* h2b = (unsigned short*)(ws + 8000000);     // [8.0M,10.0M) N*40 bf16
    float* as2 = ws + 10000000;                                // [10.0M,10.1M)
    float* ad2 = ws + 10100000;                                // [10.1M,10.2M)
    unsigned short* W1t = (unsigned short*)(ws + 10200000);    // 40960 ush
    unsigned short* W2t = (unsigned short*)(ws + 10250000);    // 3072 ush
    int* row_ptr = (int*)(ws + 10300000);                      // N+1
    int* deg     = (int*)(ws + 10410000);                      // N
    int* csr_src = (int*)(ws + 10630000);                      // ETOT -> ends 12.33M
    int* aggrA   = (int*)(ws + 12340000);                      // 98
    int* inclA   = (int*)(ws + 12350000);                      // 98
    unsigned int* flags = (unsigned int*)(ws + 12360000);      // 128
    int* ord     = (int*)(ws + 13000000);                      // ETOT -> ends 14.7M

    k_prep<<<391, 256, 0, stream>>>(W1, at_s1, at_d1, W2, at_s2, at_d2, W1t, W2t, deg, flags);
    k_g1deg<<<DEG_NB + GEMM1_NB, 256, 0, stream>>>(x, W1t, h1b, as1, ad1, ei, deg, ord);
    k_scan_lb<<<SCAN_NB2, 1024, 0, stream>>>(deg, row_ptr, aggrA, inclA, flags);
    k_scatter<<<(ETOT + 255) / 256, 256, 0, stream>>>(ei, row_ptr, ord, csr_src);
    k_agg1f<<<N_NODES / 4, 256, 0, stream>>>(h1b, as1, ad1, row_ptr, csr_src, b1, W2t,
                                             h2b, as2, ad2);
    k_agg2<<<(N_NODES + 3) / 4, 256, 0, stream>>>(h2b, as2, ad2, row_ptr, csr_src, b2, out);
}

// Round 6
// 562.361 us; speedup vs baseline: 1.2852x; 1.2852x over previous
//
#include <hip/hip_runtime.h>
#include <cstdint>

#define N_NODES 100000
#define N_EDGES 1600000
#define ETOT    1700000   // edges + self loops
#define FIN     512
#define HD1     64        // 8 heads * 8 dims
#define C2      40
#define NEG_SLOPE 0.2f
#define GEMM1_NB 782      // ceil(N_NODES/128)
#define ESL      2174     // ceil(ETOT/GEMM1_NB) edges per block's atomic slice
#define SCAN_NB2 98       // ceil(N_NODES/1024), all-resident lookback scan

typedef __attribute__((ext_vector_type(8))) short bf16x8;
typedef __attribute__((ext_vector_type(4))) float f32x4;

__device__ __forceinline__ float lrelu(float v) { return v > 0.f ? v : NEG_SLOPE * v; }

__device__ __forceinline__ unsigned short f2bf(float f) {
    uint32_t u = __float_as_uint(f);
    u += 0x7FFF + ((u >> 16) & 1);   // round-to-nearest-even
    return (unsigned short)(u >> 16);
}
__device__ __forceinline__ float bf2f(unsigned short u) {
    return __uint_as_float(((uint32_t)u) << 16);
}

// ---------------- prep (merged) + zero deg + zero scan flags ----------------
__global__ void k_prep(const float* __restrict__ W1, const float* __restrict__ a_s,
                       const float* __restrict__ a_d,
                       const float* __restrict__ W2, const float* __restrict__ att_s2,
                       const float* __restrict__ att_d2,
                       unsigned short* __restrict__ W1t, unsigned short* __restrict__ W2t,
                       int* __restrict__ deg, unsigned int* __restrict__ flags) {
    int i = blockIdx.x * 256 + threadIdx.x;
    if (i < N_NODES) deg[i] = 0;
    if (i < 128) flags[i] = 0u;
    if (i < 80 * 512) {
        int n = i >> 9, k = i & 511;
        float v;
        if (n < 64) {
            v = W1[k * HD1 + n];
        } else if (n < 72) {
            int h = n - 64; v = 0.f;
#pragma unroll
            for (int d = 0; d < 8; d++) v += W1[k * HD1 + h * 8 + d] * a_s[h * 8 + d];
        } else {
            int h = n - 72; v = 0.f;
#pragma unroll
            for (int d = 0; d < 8; d++) v += W1[k * HD1 + h * 8 + d] * a_d[h * 8 + d];
        }
        W1t[n * FIN + k] = f2bf(v);
    } else if (i < 80 * 512 + 48 * 64) {
        int j = i - 80 * 512;
        int n = j >> 6, k = j & 63;
        float v = 0.f;
        if (n < C2) {
            v = W2[k * C2 + n];
        } else if (n == C2) {
            for (int c = 0; c < C2; c++) v += W2[k * C2 + c] * att_s2[c];
        } else if (n == C2 + 1) {
            for (int c = 0; c < C2; c++) v += W2[k * C2 + c] * att_d2[c];
        }
        W2t[n * 64 + k] = f2bf(v);
    }
}

// ---------------- merged GEMM1 + degord, fine-grained interleave ----------------
// Each block owns gemm tile bid AND atomic-slice [bid*ESL, bid*ESL+ESL).
// Even blocks: atomics then gemm; odd blocks: gemm then atomics -> at steady state
// ~half the resident waves stream MFMA/HBM while ~half sit on L2 atomic latency.
__global__ __launch_bounds__(256) void k_g1deg(const float* __restrict__ x,
                                               const unsigned short* __restrict__ W1t,
                                               unsigned short* __restrict__ h1b,
                                               float* __restrict__ as1,
                                               float* __restrict__ ad1,
                                               const int* __restrict__ ei,
                                               int* __restrict__ deg,
                                               int* __restrict__ ord) {
    __shared__ unsigned short As[128 * 72];   // chunk of x in bf16, row stride 72 (pad 8)
    const int t   = threadIdx.x;
    const int bid = blockIdx.x;
    const int e0 = bid * ESL;
    const int e1 = (e0 + ESL < ETOT) ? e0 + ESL : ETOT;
    const bool atomFirst = (bid & 1) == 0;

    if (atomFirst) {
        for (int e = e0 + t; e < e1; e += 256) {
            int dst = (e < N_EDGES) ? ei[N_EDGES + e] : e - N_EDGES;
            ord[e] = atomicAdd(&deg[dst], 1);
        }
    }

    const int lane = t & 63, wv = t >> 6;
    const int quad = lane >> 4, l16 = lane & 15;
    const int row0 = bid * 128;

    f32x4 acc[2][5];
#pragma unroll
    for (int mi = 0; mi < 2; mi++)
#pragma unroll
        for (int ni = 0; ni < 5; ni++) acc[mi][ni] = (f32x4){0.f, 0.f, 0.f, 0.f};

    float4 rx[8];
#pragma unroll
    for (int i = 0; i < 8; i++) {
        int ff = t + i * 256;
        int r = ff >> 4, c4 = ff & 15;
        int row = row0 + r;
        rx[i] = (row < N_NODES) ? *(const float4*)&x[(size_t)row * FIN + c4 * 4]
                                : make_float4(0.f, 0.f, 0.f, 0.f);
    }

    for (int c = 0; c < 8; c++) {
#pragma unroll
        for (int i = 0; i < 8; i++) {
            int ff = t + i * 256;
            int r = ff >> 4, c4 = ff & 15;
            ushort4 s4;
            s4.x = f2bf(rx[i].x); s4.y = f2bf(rx[i].y);
            s4.z = f2bf(rx[i].z); s4.w = f2bf(rx[i].w);
            *(ushort4*)&As[r * 72 + c4 * 4] = s4;
        }
        __syncthreads();
        if (c < 7) {
            int kb = (c + 1) * 64;
#pragma unroll
            for (int i = 0; i < 8; i++) {
                int ff = t + i * 256;
                int r = ff >> 4, c4 = ff & 15;
                int row = row0 + r;
                rx[i] = (row < N_NODES) ? *(const float4*)&x[(size_t)row * FIN + kb + c4 * 4]
                                        : make_float4(0.f, 0.f, 0.f, 0.f);
            }
        }
        int kb = c * 64;
#pragma unroll
        for (int ks = 0; ks < 2; ks++) {
            bf16x8 af[2], bfv[5];
#pragma unroll
            for (int mi = 0; mi < 2; mi++) {
                int lr = wv * 32 + mi * 16 + l16;
                af[mi] = *(const bf16x8*)&As[lr * 72 + ks * 32 + quad * 8];
            }
#pragma unroll
            for (int ni = 0; ni < 5; ni++) {
                int n = ni * 16 + l16;
                bfv[ni] = *(const bf16x8*)&W1t[n * FIN + kb + ks * 32 + quad * 8];
            }
#pragma unroll
            for (int mi = 0; mi < 2; mi++)
#pragma unroll
                for (int ni = 0; ni < 5; ni++)
                    acc[mi][ni] = __builtin_amdgcn_mfma_f32_16x16x32_bf16(
                        af[mi], bfv[ni], acc[mi][ni], 0, 0, 0);
        }
        __syncthreads();
    }
#pragma unroll
    for (int mi = 0; mi < 2; mi++)
#pragma unroll
        for (int ni = 0; ni < 5; ni++)
#pragma unroll
            for (int r = 0; r < 4; r++) {
                int row = row0 + wv * 32 + mi * 16 + quad * 4 + r;
                if (row >= N_NODES) continue;
                int col = ni * 16 + l16;
                float v = acc[mi][ni][r];
                if (col < 64)       h1b[(size_t)row * 64 + col] = f2bf(v);
                else if (col < 72)  as1[row * 8 + (col - 64)] = v;
                else                ad1[row * 8 + (col - 72)] = v;
            }

    if (!atomFirst) {
        for (int e = e0 + t; e < e1; e += 256) {
            int dst = (e < N_EDGES) ? ei[N_EDGES + e] : e - N_EDGES;
            ord[e] = atomicAdd(&deg[dst], 1);
        }
    }
}

// ---------------- single-kernel decoupled-lookback scan: deg -> row_ptr (exclusive) ------
// 98 blocks <= 256 CUs -> all blocks co-resident -> predecessor spin always terminates.
__global__ __launch_bounds__(1024) void k_scan_lb(const int* __restrict__ deg,
                                                  int* __restrict__ row_ptr,
                                                  int* __restrict__ aggr,
                                                  int* __restrict__ incl,
                                                  unsigned int* __restrict__ flags) {
    __shared__ int sh[1024];
    __shared__ int shbase;
    const int t = threadIdx.x, b = blockIdx.x;
    const int i = b * 1024 + t;
    int v = (i < N_NODES) ? deg[i] : 0;
    sh[t] = v;
    __syncthreads();
    for (int off = 1; off < 1024; off <<= 1) {
        int u = (t >= off) ? sh[t - off] : 0;
        __syncthreads();
        sh[t] += u;
        __syncthreads();
    }
    if (t == 0) {
        int total = sh[1023];
        int run = 0;
        if (b == 0) {
            __hip_atomic_store(&incl[0], total, __ATOMIC_RELEASE, __HIP_MEMORY_SCOPE_AGENT);
            __hip_atomic_store(&flags[0], 2u, __ATOMIC_RELEASE, __HIP_MEMORY_SCOPE_AGENT);
        } else {
            __hip_atomic_store(&aggr[b], total, __ATOMIC_RELEASE, __HIP_MEMORY_SCOPE_AGENT);
            __hip_atomic_store(&flags[b], 1u, __ATOMIC_RELEASE, __HIP_MEMORY_SCOPE_AGENT);
            int p = b - 1;
            while (true) {
                unsigned int f = __hip_atomic_load(&flags[p], __ATOMIC_ACQUIRE,
                                                   __HIP_MEMORY_SCOPE_AGENT);
                if (f == 2u) {
                    run += __hip_atomic_load(&incl[p], __ATOMIC_ACQUIRE,
                                             __HIP_MEMORY_SCOPE_AGENT);
                    break;
                } else if (f == 1u) {
                    run += __hip_atomic_load(&aggr[p], __ATOMIC_ACQUIRE,
                                             __HIP_MEMORY_SCOPE_AGENT);
                    --p;
                }
            }
            __hip_atomic_store(&incl[b], run + total, __ATOMIC_RELEASE,
                               __HIP_MEMORY_SCOPE_AGENT);
            __hip_atomic_store(&flags[b], 2u, __ATOMIC_RELEASE, __HIP_MEMORY_SCOPE_AGENT);
        }
        shbase = run;
        if (b == 0) row_ptr[N_NODES] = ETOT;   // scan total is a compile-time constant
    }
    __syncthreads();
    int base = shbase;
    if (i < N_NODES) row_ptr[i] = base + sh[t] - v;
}

// scatter with precomputed rank — no atomics
__global__ void k_scatter(const int* __restrict__ ei, const int* __restrict__ row_ptr,
                          const int* __restrict__ ord, int* __restrict__ csr_src) {
    int e = blockIdx.x * 256 + threadIdx.x;
    if (e >= ETOT) return;
    int src, dst;
    if (e < N_EDGES) { src = ei[e]; dst = ei[N_EDGES + e]; }
    else             { src = dst = e - N_EDGES; }
    csr_src[row_ptr[dst] + ord[e]] = src;
}

// ---------------- layer 1: gather-aggregate + bias + ELU -> hb (bf16) ----------------
// one wave per dst; lane = (edge-slot g = lane>>3, head i8 = lane&7)
// 16 edges in flight per step (two independent 8-edge groups).
__global__ __launch_bounds__(256) void k_agg1(
    const unsigned short* __restrict__ h1b,
    const float* __restrict__ as1, const float* __restrict__ ad1,
    const int* __restrict__ row_ptr, const int* __restrict__ csr_src,
    const float* __restrict__ b1, unsigned short* __restrict__ hb) {
    int t = threadIdx.x, wv = t >> 6, lane = t & 63;
    int dst = blockIdx.x * 4 + wv;
    if (dst >= N_NODES) return;
    int g = lane >> 3, i8 = lane & 7;
    int s0 = row_ptr[dst], s1e = row_ptr[dst + 1];
    float adh = ad1[dst * 8 + i8];
    float den = 0.f;
    float facc[8];
#pragma unroll
    for (int d = 0; d < 8; d++) facc[d] = 0.f;

    for (int base = s0; base < s1e; base += 64) {
        int idx = base + lane;
        int sl = (idx < s1e) ? csr_src[idx] : 0;
        int cnt = min(64, s1e - base);
        for (int j = 0; j < cnt; j += 16) {
            int sA = __shfl(sl, j + g);
            int sB = __shfl(sl, j + 8 + g);
            bool vA = (j + g) < cnt, vB = (j + 8 + g) < cnt;
            bf16x8 rA = *(const bf16x8*)&h1b[(size_t)sA * 64 + i8 * 8];
            bf16x8 rB = *(const bf16x8*)&h1b[(size_t)sB * 64 + i8 * 8];
            float aA = as1[sA * 8 + i8];
            float aB = as1[sB * 8 + i8];
            float wA = vA ? __expf(lrelu(aA + adh)) : 0.f;
            float wB = vB ? __expf(lrelu(aB + adh)) : 0.f;
            den += wA + wB;
#pragma unroll
            for (int d = 0; d < 8; d++)
                facc[d] += wA * bf2f((unsigned short)rA[d]) +
                           wB * bf2f((unsigned short)rB[d]);
        }
    }
    // reduce across edge-slots g (lane bits 3..5)
#pragma unroll
    for (int o = 8; o <= 32; o <<= 1) {
        den += __shfl_xor(den, o, 64);
#pragma unroll
        for (int d = 0; d < 8; d++) facc[d] += __shfl_xor(facc[d], o, 64);
    }
    float rden = 1.f / (den + 1e-16f);
    float4 b1lo = *(const float4*)&b1[i8 * 8];
    float4 b1hi = *(const float4*)&b1[i8 * 8 + 4];
    float bb[8] = {b1lo.x, b1lo.y, b1lo.z, b1lo.w, b1hi.x, b1hi.y, b1hi.z, b1hi.w};
    bf16x8 pk;
#pragma unroll
    for (int d = 0; d < 8; d++) {
        float hv = facc[d] * rden + bb[d];
        hv = hv > 0.f ? hv : expm1f(hv);
        pk[d] = (short)f2bf(hv);
    }
    if (g == 0) *(bf16x8*)&hb[(size_t)dst * 64 + i8 * 8] = pk;
}

// ---------------- GEMM2 (MFMA bf16): [h2b | as2 | ad2] = hb @ W2t^T ----------------
__global__ __launch_bounds__(256) void k_gemm2(const unsigned short* __restrict__ hb,
                                               const unsigned short* __restrict__ W2t,
                                               unsigned short* __restrict__ h2b,
                                               float* __restrict__ as2,
                                               float* __restrict__ ad2) {
    const int t = threadIdx.x;
    const int lane = t & 63, wv = t >> 6;
    const int quad = lane >> 4, l16 = lane & 15;
    const int row0 = blockIdx.x * 128;

    f32x4 acc[2][3];
#pragma unroll
    for (int mi = 0; mi < 2; mi++)
#pragma unroll
        for (int ni = 0; ni < 3; ni++) acc[mi][ni] = (f32x4){0.f, 0.f, 0.f, 0.f};

    bf16x8 bfrag[2][3];
#pragma unroll
    for (int ks = 0; ks < 2; ks++)
#pragma unroll
        for (int ni = 0; ni < 3; ni++)
            bfrag[ks][ni] = *(const bf16x8*)&W2t[(ni * 16 + l16) * 64 + ks * 32 + quad * 8];

#pragma unroll
    for (int mi = 0; mi < 2; mi++) {
        int row = row0 + wv * 32 + mi * 16 + l16;
        int rowc = row < N_NODES ? row : N_NODES - 1;   // clamp (epilogue masks)
#pragma unroll
        for (int ks = 0; ks < 2; ks++) {
            bf16x8 af = *(const bf16x8*)&hb[(size_t)rowc * 64 + ks * 32 + quad * 8];
#pragma unroll
            for (int ni = 0; ni < 3; ni++)
                acc[mi][ni] = __builtin_amdgcn_mfma_f32_16x16x32_bf16(
                    af, bfrag[ks][ni], acc[mi][ni], 0, 0, 0);
        }
    }
#pragma unroll
    for (int mi = 0; mi < 2; mi++)
#pragma unroll
        for (int ni = 0; ni < 3; ni++)
#pragma unroll
            for (int r = 0; r < 4; r++) {
                int row = row0 + wv * 32 + mi * 16 + quad * 4 + r;
                if (row >= N_NODES) continue;
                int col = ni * 16 + l16;
                float v = acc[mi][ni][r];
                if (col < C2)            h2b[(size_t)row * C2 + col] = f2bf(v);
                else if (col == C2)      as2[row] = v;
                else if (col == C2 + 1)  ad2[row] = v;
            }
}

// ---------------- layer 2: gather-aggregate + bias + log_softmax ----------------
// one wave per dst; lane = (edge-slot g = lane>>3, chunk i8 = lane&7); chunks 0..4 active
// 16 edges per step (two independent 8-edge groups).
__global__ __launch_bounds__(256) void k_agg2(
    const unsigned short* __restrict__ h2b,
    const float* __restrict__ as2, const float* __restrict__ ad2,
    const int* __restrict__ row_ptr, const int* __restrict__ csr_src,
    const float* __restrict__ b2, float* __restrict__ out) {
    int t = threadIdx.x, wv = t >> 6, lane = t & 63;
    int dst = blockIdx.x * 4 + wv;
    if (dst >= N_NODES) return;
    int g = lane >> 3, i8 = lane & 7;
    bool act = i8 < 5;
    int off = act ? i8 * 8 : 0;
    int s0 = row_ptr[dst], s1e = row_ptr[dst + 1];
    float ad = ad2[dst];
    float denp = 0.f;
    float facc[8];
#pragma unroll
    for (int d = 0; d < 8; d++) facc[d] = 0.f;

    for (int base = s0; base < s1e; base += 64) {
        int idx = base + lane;
        int sl = (idx < s1e) ? csr_src[idx] : 0;
        int cnt = min(64, s1e - base);
        for (int j = 0; j < cnt; j += 16) {
            int sA = __shfl(sl, j + g);
            int sB = __shfl(sl, j + 8 + g);
            bool vA = (j + g) < cnt, vB = (j + 8 + g) < cnt;
            bf16x8 rA = *(const bf16x8*)&h2b[(size_t)sA * C2 + off];
            bf16x8 rB = *(const bf16x8*)&h2b[(size_t)sB * C2 + off];
            float aA = as2[sA];
            float aB = as2[sB];
            float wfA = vA ? __expf(lrelu(aA + ad)) : 0.f;
            float wfB = vB ? __expf(lrelu(aB + ad)) : 0.f;
            if (i8 == 0) denp += wfA + wfB;                // each edge counted once
            float wA = act ? wfA : 0.f;
            float wB = act ? wfB : 0.f;
#pragma unroll
            for (int d = 0; d < 8; d++)
                facc[d] += wA * bf2f((unsigned short)rA[d]) +
                           wB * bf2f((unsigned short)rB[d]);
        }
    }
    // facc: reduce across edge-slots g (bits 3..5)
#pragma unroll
    for (int o = 8; o <= 32; o <<= 1)
#pragma unroll
        for (int d = 0; d < 8; d++) facc[d] += __shfl_xor(facc[d], o, 64);
    // den: full 64-lane butterfly of the i8==0 partials
    float den = denp;
#pragma unroll
    for (int o = 32; o >= 1; o >>= 1) den += __shfl_xor(den, o, 64);
    float rden = 1.f / (den + 1e-16f);

    float vch[8];
    float mx = -1e30f;
#pragma unroll
    for (int d = 0; d < 8; d++) {
        vch[d] = act ? facc[d] * rden + b2[off + d] : -1e30f;
        mx = fmaxf(mx, vch[d]);
    }
#pragma unroll
    for (int o = 1; o <= 4; o <<= 1) mx = fmaxf(mx, __shfl_xor(mx, o, 64));
    float es = 0.f;
#pragma unroll
    for (int d = 0; d < 8; d++) es += act ? __expf(vch[d] - mx) : 0.f;
#pragma unroll
    for (int o = 1; o <= 4; o <<= 1) es += __shfl_xor(es, o, 64);
    float lg = logf(es);
    if (g == 0 && act) {
        float4 o0 = {vch[0] - mx - lg, vch[1] - mx - lg, vch[2] - mx - lg, vch[3] - mx - lg};
        float4 o1 = {vch[4] - mx - lg, vch[5] - mx - lg, vch[6] - mx - lg, vch[7] - mx - lg};
        *(float4*)&out[(size_t)dst * C2 + i8 * 8]     = o0;
        *(float4*)&out[(size_t)dst * C2 + i8 * 8 + 4] = o1;
    }
}

extern "C" void kernel_launch(void* const* d_in, const int* in_sizes, int n_in,
                              void* d_out, int out_size, void* d_ws, size_t ws_size,
                              hipStream_t stream) {
    const float* x     = (const float*)d_in[0];
    const int*   ei    = (const int*)d_in[1];
    const float* W1    = (const float*)d_in[2];
    const float* at_s1 = (const float*)d_in[3];
    const float* at_d1 = (const float*)d_in[4];
    const float* b1    = (const float*)d_in[5];
    const float* W2    = (const float*)d_in[6];
    const float* at_s2 = (const float*)d_in[7];
    const float* at_d2 = (const float*)d_in[8];
    const float* b2    = (const float*)d_in[9];
    float* out = (float*)d_out;
    float* ws  = (float*)d_ws;

    // workspace layout (float-element offsets) — NON-OVERLAPPING:
    unsigned short* h1b = (unsigned short*)ws;                 // [0, 3.2M)  N*64 bf16
    float* as1 = ws + 3200000;                                 // [3.2M,4.0M)
    float* ad1 = ws + 4000000;                                 // [4.0M,4.8M)
    unsigned short* hb  = (unsigned short*)(ws + 4800000);     // [4.8M,8.0M) N*64 bf16
    unsigned short* h2b = (unsigned short*)(ws + 8000000);     // [8.0M,10.0M) N*40 bf16
    float* as2 = ws + 10000000;                                // [10.0M,10.1M)
    float* ad2 = ws + 10100000;                                // [10.1M,10.2M)
    unsigned short* W1t = (unsigned short*)(ws + 10200000);    // 40960 ush
    unsigned short* W2t = (unsigned short*)(ws + 10250000);    // 3072 ush
    int* row_ptr = (int*)(ws + 10300000);                      // N+1
    int* deg     = (int*)(ws + 10410000);                      // N
    int* csr_src = (int*)(ws + 10630000);                      // ETOT -> ends 12.33M
    int* aggrA   = (int*)(ws + 12340000);                      // 98
    int* inclA   = (int*)(ws + 12350000);                      // 98
    unsigned int* flags = (unsigned int*)(ws + 12360000);      // 128
    int* ord     = (int*)(ws + 13000000);                      // ETOT -> ends 14.7M

    k_prep<<<391, 256, 0, stream>>>(W1, at_s1, at_d1, W2, at_s2, at_d2, W1t, W2t, deg, flags);
    k_g1deg<<<GEMM1_NB, 256, 0, stream>>>(x, W1t, h1b, as1, ad1, ei, deg, ord);
    k_scan_lb<<<SCAN_NB2, 1024, 0, stream>>>(deg, row_ptr, aggrA, inclA, flags);
    k_scatter<<<(ETOT + 255) / 256, 256, 0, stream>>>(ei, row_ptr, ord, csr_src);
    k_agg1<<<(N_NODES + 3) / 4, 256, 0, stream>>>(h1b, as1, ad1, row_ptr, csr_src, b1, hb);
    k_gemm2<<<(N_NODES + 127) / 128, 256, 0, stream>>>(hb, W2t, h2b, as2, ad2);
    k_agg2<<<(N_NODES + 3) / 4, 256, 0, stream>>>(h2b, as2, ad2, row_ptr, csr_src, b2, out);
}